// Round 5
// baseline (362.757 us; speedup 1.0000x reference)
//
#include <hip/hip_runtime.h>
#include <hip/hip_bf16.h>
#include <hip/hip_fp16.h>
#include <stdint.h>

#define B_SIZE 8192
#define D_SIZE 2048
#define C_SIZE 128
#define N_INNER 255
#define N_LEAF 256
#define NPAD 256

typedef _Float16 half8 __attribute__((ext_vector_type(8)));
typedef __fp16 pk16x2 __attribute__((ext_vector_type(2)));   // return type of cvt_pkrtz
typedef float f32x4 __attribute__((ext_vector_type(4)));
typedef unsigned short u16;

// ---- fp32 -> (hi,lo) fp16 split, packed pairs ----
__device__ inline uint32_t pkh(float a, float b) {
    pk16x2 h = __builtin_amdgcn_cvt_pkrtz(a, b);
    return __builtin_bit_cast(uint32_t, h);
}
__device__ inline void split4(const float4 v, uint2& hi, uint2& lo) {
    pk16x2 a01 = __builtin_amdgcn_cvt_pkrtz(v.x, v.y);
    pk16x2 a23 = __builtin_amdgcn_cvt_pkrtz(v.z, v.w);
    float r0 = v.x - (float)a01[0];
    float r1 = v.y - (float)a01[1];
    float r2 = v.z - (float)a23[0];
    float r3 = v.w - (float)a23[1];
    hi = make_uint2(__builtin_bit_cast(uint32_t, a01), __builtin_bit_cast(uint32_t, a23));
    lo = make_uint2(pkh(r0, r1), pkh(r2, r3));
}

// ---- async global->LDS, 16B per lane; lds base must be wave-uniform ----
__device__ inline void llds16(const u16* g, u16* l) {
    __builtin_amdgcn_global_load_lds(
        (const __attribute__((address_space(1))) void*)g,
        (__attribute__((address_space(3))) void*)l, 16, 0, 0);
}

// ---------------- K-pre: split W fp32 -> Wh/Wl f16 (padded to 256 rows, row 255 = 0) ----------------
__global__ __launch_bounds__(256) void split_w_kernel(
    const float* __restrict__ Wsrc, u16* __restrict__ Wh, u16* __restrict__ Wl)
{
    int row = blockIdx.x;          // 0..255
    int t = threadIdx.x;           // 0..255, each handles 8 k
    int k = t * 8;
    uint2 h0, l0, h1, l1;
    if (row < N_INNER) {
        float4 v0 = *(const float4*)(Wsrc + (size_t)row * D_SIZE + k);
        float4 v1 = *(const float4*)(Wsrc + (size_t)row * D_SIZE + k + 4);
        split4(v0, h0, l0); split4(v1, h1, l1);
    } else {
        h0 = l0 = h1 = l1 = make_uint2(0u, 0u);
    }
    *(uint2*)&Wh[(size_t)row * D_SIZE + k]     = h0;
    *(uint2*)&Wh[(size_t)row * D_SIZE + k + 4] = h1;
    *(uint2*)&Wl[(size_t)row * D_SIZE + k]     = l0;
    *(uint2*)&Wl[(size_t)row * D_SIZE + k + 4] = l1;
}

// ---------------- K0: softmax over leaf_params rows -> Q, logQt (transposed) ----------------
__global__ __launch_bounds__(128) void softmax_kernel(
    const float* __restrict__ lp, float* __restrict__ Q, float* __restrict__ logQt)
{
    int row = blockIdx.x;      // leaf
    int t = threadIdx.x;       // class
    __shared__ float red[128];
    float v = lp[row * C_SIZE + t];
    red[t] = v; __syncthreads();
    for (int s = 64; s > 0; s >>= 1) { if (t < s) red[t] = fmaxf(red[t], red[t + s]); __syncthreads(); }
    float mx = red[0]; __syncthreads();
    float e = expf(v - mx);
    red[t] = e; __syncthreads();
    for (int s = 64; s > 0; s >>= 1) { if (t < s) red[t] += red[t + s]; __syncthreads(); }
    float sum = red[0];
    Q[row * C_SIZE + t] = e / sum;
    logQt[(size_t)t * N_LEAF + row] = (v - mx) - logf(sum);   // [class][leaf]
}

// ---------------- K1: z_part[kz] = x @ W^T partials, fp16-split MFMA ----------------
// BM=64 (4 m-frags), BN=256 (full N: 4 waves x 64 cols), BK=32, KSPLIT=4.
// x is read exactly once. W (pre-split, 2 MB) stays L2-resident.
#define GBM 64
#define GBN 256
#define GBK 32
#define GKSPLIT 4
#define KCHUNK (D_SIZE / GKSPLIT)   // 512
#define LDKA 40   // padded A row stride in u16 (80 B)
#define LDKB 32   // B row stride in u16 (64 B), XOR-swizzled 8-element chunks

__global__ __launch_bounds__(256, 2) void gemm_mfma(
    const float* __restrict__ x, const u16* __restrict__ Wh, const u16* __restrict__ Wl,
    float* __restrict__ zp)
{
    __shared__ __align__(16) u16 sAh[GBM * LDKA];
    __shared__ __align__(16) u16 sAl[GBM * LDKA];
    __shared__ __align__(16) u16 sBh[GBN * LDKB];
    __shared__ __align__(16) u16 sBl[GBN * LDKB];

    const int t = threadIdx.x;
    const int lane = t & 63, w = t >> 6;
    const int lr = lane & 15, lq = lane >> 4;
    const int m0 = blockIdx.x * GBM;
    const int kz = blockIdx.z;

    f32x4 acc[4][4];
    #pragma unroll
    for (int mt = 0; mt < 4; ++mt)
        #pragma unroll
        for (int nt = 0; nt < 4; ++nt) acc[mt][nt] = (f32x4){0.f, 0.f, 0.f, 0.f};

    // B staging source mapping: lane l writes LDS row (base + (l>>2)), chunk position l&3.
    // Swizzle: logical chunk c stored at position c ^ ((row>>1)&3); row>>1 mod 4 = (l>>3)&3.
    const int brow = lane >> 2;                          // 0..15 within 16-row group
    const int bchunk = (lane & 3) ^ ((lane >> 3) & 3);   // source logical chunk
    const int arow0 = t >> 3, akq = t & 7;               // A load mapping

    for (int kt = 0; kt < KCHUNK / GBK; ++kt) {
        const int kb = kz * KCHUNK + kt * GBK;
        __syncthreads();
        // A: 2 float4 register loads per thread
        float4 av0 = *(const float4*)(x + (size_t)(m0 + arow0) * D_SIZE + kb + akq * 4);
        float4 av1 = *(const float4*)(x + (size_t)(m0 + 32 + arow0) * D_SIZE + kb + akq * 4);
        // B: async global->LDS, 16 rows per issue, 4 issues each for hi/lo per wave
        #pragma unroll
        for (int g = 0; g < 4; ++g) {
            int rowbase = w * 64 + g * 16;
            const u16* srcH = Wh + (size_t)(rowbase + brow) * D_SIZE + kb + bchunk * 8;
            llds16(srcH, &sBh[rowbase * LDKB]);
        }
        #pragma unroll
        for (int g = 0; g < 4; ++g) {
            int rowbase = w * 64 + g * 16;
            const u16* srcL = Wl + (size_t)(rowbase + brow) * D_SIZE + kb + bchunk * 8;
            llds16(srcL, &sBl[rowbase * LDKB]);
        }
        // split A into LDS
        {
            uint2 hi, lo;
            split4(av0, hi, lo);
            *(uint2*)&sAh[arow0 * LDKA + akq * 4] = hi;
            *(uint2*)&sAl[arow0 * LDKA + akq * 4] = lo;
            split4(av1, hi, lo);
            *(uint2*)&sAh[(arow0 + 32) * LDKA + akq * 4] = hi;
            *(uint2*)&sAl[(arow0 + 32) * LDKA + akq * 4] = lo;
        }
        __syncthreads();

        half8 ah[4], al[4], bh[4], bl[4];
        #pragma unroll
        for (int mt = 0; mt < 4; ++mt) {
            int off = (mt * 16 + lr) * LDKA + lq * 8;
            ah[mt] = *(const half8*)&sAh[off];
            al[mt] = *(const half8*)&sAl[off];
        }
        const int sw = (lr >> 1) & 3;
        #pragma unroll
        for (int nt = 0; nt < 4; ++nt) {
            int row = w * 64 + nt * 16 + lr;
            int off = row * LDKB + ((lq ^ sw) * 8);
            bh[nt] = *(const half8*)&sBh[off];
            bl[nt] = *(const half8*)&sBl[off];
        }
        #pragma unroll
        for (int mt = 0; mt < 4; ++mt)
            #pragma unroll
            for (int nt = 0; nt < 4; ++nt) {
                acc[mt][nt] = __builtin_amdgcn_mfma_f32_16x16x32_f16(ah[mt], bh[nt], acc[mt][nt], 0, 0, 0);
                acc[mt][nt] = __builtin_amdgcn_mfma_f32_16x16x32_f16(ah[mt], bl[nt], acc[mt][nt], 0, 0, 0);
                acc[mt][nt] = __builtin_amdgcn_mfma_f32_16x16x32_f16(al[mt], bh[nt], acc[mt][nt], 0, 0, 0);
            }
    }

    float* zout = zp + (size_t)kz * B_SIZE * NPAD;
    #pragma unroll
    for (int mt = 0; mt < 4; ++mt) {
        #pragma unroll
        for (int nt = 0; nt < 4; ++nt) {
            int gn = w * 64 + nt * 16 + lr;
            #pragma unroll
            for (int r = 0; r < 4; ++r) {
                int gm = m0 + mt * 16 + lq * 4 + r;
                zout[(size_t)gm * NPAD + gn] = acc[mt][nt][r];
            }
        }
    }
}

// ---------------- K2: fused reduce + sigmoid + paths + penalties + loss + argmax gather ----------------
// 512 blocks x 4 waves; each wave handles 4 rows. pbuf is wave-private.
__global__ __launch_bounds__(256) void path_kernel(
    const float* __restrict__ z, const int* __restrict__ target,
    const float* __restrict__ bvec, const float* __restrict__ beta,
    const float* __restrict__ Q, const float* __restrict__ logQt,
    float* __restrict__ g_num, float* __restrict__ g_den,
    float* __restrict__ g_loss, float* __restrict__ out)
{
    __shared__ float pbuf[4][256];
    const int t = threadIdx.x, w = t >> 6, lane = t & 63;
    const int c0 = lane * 4;
    float pnum[4] = {0.f, 0.f, 0.f, 0.f};
    float pden[4] = {0.f, 0.f, 0.f, 0.f};
    float loss = 0.f;

    float bet[4], bia[4];
    #pragma unroll
    for (int j = 0; j < 4; ++j) {
        int c = c0 + j;
        bet[j] = (c < N_INNER) ? beta[c] : 0.f;
        bia[j] = (c < N_INNER) ? bvec[c] : 0.f;
    }

    for (int i = 0; i < 4; ++i) {
        int r = blockIdx.x * 16 + w * 4 + i;
        // sum split-K partials (coalesced float4)
        float4 s = make_float4(0.f, 0.f, 0.f, 0.f);
        #pragma unroll
        for (int p = 0; p < GKSPLIT; ++p) {
            float4 v = *(const float4*)(z + ((size_t)p * B_SIZE + r) * NPAD + c0);
            s.x += v.x; s.y += v.y; s.z += v.z; s.w += v.w;
        }
        float zv[4] = {s.x, s.y, s.z, s.w};
        float pv[4];
        #pragma unroll
        for (int j = 0; j < 4; ++j) {
            int c = c0 + j;
            pv[j] = (c < N_INNER) ? 1.f / (1.f + expf(-bet[j] * (zv[j] + bia[j]))) : 0.f;
        }
        *(float4*)&pbuf[w][c0] = make_float4(pv[0], pv[1], pv[2], pv[3]);
        __syncthreads();

        int tg = target[r];
        float4 lq4 = *(const float4*)(logQt + (size_t)tg * N_LEAF + c0);
        float lqa[4] = {lq4.x, lq4.y, lq4.z, lq4.w};
        float lsum = 0.f, bestV = -1.f;
        int bestI = 0;
        #pragma unroll
        for (int j = 0; j < 4; ++j) {
            int leaf = c0 + j;
            float pl = 1.f;
            #pragma unroll
            for (int d = 0; d < 8; ++d) {
                int node = (1 << d) - 1 + (leaf >> (8 - d));
                int bit = (leaf >> (7 - d)) & 1;
                float pvn = pbuf[w][node];
                pl *= bit ? pvn : (1.f - pvn);
            }
            lsum += pl * lqa[j];
            if (pl > bestV) { bestV = pl; bestI = leaf; }  // ascending j keeps lowest tie
        }
        // penalties: lanes 0..31 own nodes c0..c0+3 (<127)
        if (lane < 32) {
            #pragma unroll
            for (int j = 0; j < 4; ++j) {
                int c = c0 + j;
                if (c < 127) {
                    int h = c + 1; int d = 31 - __clz(h);
                    float pp = 1.f;
                    for (int e = 0; e < d; ++e) {
                        int ha = h >> (d - e);
                        int bit = (h >> (d - 1 - e)) & 1;
                        float pvn = pbuf[w][ha - 1];
                        pp *= bit ? pvn : (1.f - pvn);
                    }
                    pnum[j] += pbuf[w][c] * pp;
                    pden[j] += pp;
                }
            }
        }
        // wave reductions (sum + argmax, lowest-index tie-break)
        #pragma unroll
        for (int m = 1; m < 64; m <<= 1) {
            lsum += __shfl_xor(lsum, m, 64);
            float ov = __shfl_xor(bestV, m, 64);
            int   oi = __shfl_xor(bestI, m, 64);
            if (ov > bestV || (ov == bestV && oi < bestI)) { bestV = ov; bestI = oi; }
        }
        loss += lsum;
        out[1 + (size_t)r * C_SIZE + lane]      = Q[bestI * C_SIZE + lane];
        out[1 + (size_t)r * C_SIZE + lane + 64] = Q[bestI * C_SIZE + lane + 64];
        __syncthreads();
    }

    if (lane < 32) {
        #pragma unroll
        for (int j = 0; j < 4; ++j) {
            int c = c0 + j;
            if (c < 127) {
                atomicAdd(&g_num[c], pnum[j]);
                atomicAdd(&g_den[c], pden[j]);
            }
        }
    }
    if (lane == 0) atomicAdd(g_loss, loss);
}

// ---------------- K3: finalize total ----------------
__global__ __launch_bounds__(128) void finalize_kernel(
    const float* __restrict__ g_num, const float* __restrict__ g_den,
    const float* __restrict__ g_loss, float* __restrict__ out)
{
    __shared__ float red[128];
    int t = threadIdx.x;
    float term = 0.f;
    if (t < 127) {
        int d = 31 - __clz(t + 1);
        float lam = 0.1f * exp2f(-(float)(d + 1));
        float pen = g_num[t] / g_den[t];
        term = lam * 0.5f * (logf(pen) + logf(1.f - pen));
    }
    red[t] = term; __syncthreads();
    for (int s = 64; s > 0; s >>= 1) { if (t < s) red[t] += red[t + s]; __syncthreads(); }
    if (t == 0) out[0] = -(g_loss[0] / (float)B_SIZE) - red[0];
}

extern "C" void kernel_launch(void* const* d_in, const int* in_sizes, int n_in,
                              void* d_out, int out_size, void* d_ws, size_t ws_size,
                              hipStream_t stream)
{
    const float* x    = (const float*)d_in[0];
    const int*   tgt  = (const int*)d_in[1];
    const float* W    = (const float*)d_in[2];
    const float* b    = (const float*)d_in[3];
    const float* beta = (const float*)d_in[4];
    const float* lp   = (const float*)d_in[5];
    float* out = (float*)d_out;

    // ws layout (floats): [0:128) pen_num, [128:256) pen_den, [256] loss, pad to 512,
    // z partials (4 x 8192 x 256), Q (256x128), logQt (128x256), then Wh/Wl (u16 256x2048 each)
    float* g_acc = (float*)d_ws;
    float* z     = g_acc + 512;
    float* Q     = z + (size_t)GKSPLIT * B_SIZE * NPAD;
    float* logQt = Q + (size_t)N_LEAF * C_SIZE;
    u16*   Wh    = (u16*)(logQt + (size_t)C_SIZE * N_LEAF);
    u16*   Wl    = Wh + (size_t)N_LEAF * D_SIZE;

    (void)hipMemsetAsync(d_ws, 0, 512 * sizeof(float), stream);

    split_w_kernel<<<N_LEAF, 256, 0, stream>>>(W, Wh, Wl);
    softmax_kernel<<<N_LEAF, 128, 0, stream>>>(lp, Q, logQt);

    dim3 ggrid(B_SIZE / GBM, 1, GKSPLIT);   // 128 x 1 x 4 = 512 blocks
    gemm_mfma<<<ggrid, 256, 0, stream>>>(x, Wh, Wl, z);

    path_kernel<<<B_SIZE / 16, 256, 0, stream>>>(
        z, tgt, b, beta, Q, logQt,
        g_acc, g_acc + 128, g_acc + 256, out);

    finalize_kernel<<<1, 128, 0, stream>>>(g_acc, g_acc + 128, g_acc + 256, out);
}

// Round 6
// 184.562 us; speedup vs baseline: 1.9655x; 1.9655x over previous
//
#include <hip/hip_runtime.h>
#include <hip/hip_bf16.h>
#include <hip/hip_fp16.h>
#include <stdint.h>

#define B_SIZE 8192
#define D_SIZE 2048
#define C_SIZE 128
#define N_INNER 255
#define N_LEAF 256
#define NPAD 256
#define NBLK_PATH 512

typedef _Float16 half8 __attribute__((ext_vector_type(8)));
typedef __fp16 pk16x2 __attribute__((ext_vector_type(2)));   // return type of cvt_pkrtz
typedef float f32x4 __attribute__((ext_vector_type(4)));
typedef unsigned short u16;

// ---- fp32 -> (hi,lo) fp16 split, packed pairs ----
__device__ inline uint32_t pkh(float a, float b) {
    pk16x2 h = __builtin_amdgcn_cvt_pkrtz(a, b);
    return __builtin_bit_cast(uint32_t, h);
}
__device__ inline void split4(const float4 v, uint2& hi, uint2& lo) {
    pk16x2 a01 = __builtin_amdgcn_cvt_pkrtz(v.x, v.y);
    pk16x2 a23 = __builtin_amdgcn_cvt_pkrtz(v.z, v.w);
    float r0 = v.x - (float)a01[0];
    float r1 = v.y - (float)a01[1];
    float r2 = v.z - (float)a23[0];
    float r3 = v.w - (float)a23[1];
    hi = make_uint2(__builtin_bit_cast(uint32_t, a01), __builtin_bit_cast(uint32_t, a23));
    lo = make_uint2(pkh(r0, r1), pkh(r2, r3));
}

// ---------------- K-pre: split W fp32 -> Wh/Wl f16 (padded to 256 rows, row 255 = 0) ----------------
__global__ __launch_bounds__(256) void split_w_kernel(
    const float* __restrict__ Wsrc, u16* __restrict__ Wh, u16* __restrict__ Wl)
{
    int row = blockIdx.x;          // 0..255
    int t = threadIdx.x;           // 0..255, each handles 8 k
    int k = t * 8;
    uint2 h0, l0, h1, l1;
    if (row < N_INNER) {
        float4 v0 = *(const float4*)(Wsrc + (size_t)row * D_SIZE + k);
        float4 v1 = *(const float4*)(Wsrc + (size_t)row * D_SIZE + k + 4);
        split4(v0, h0, l0); split4(v1, h1, l1);
    } else {
        h0 = l0 = h1 = l1 = make_uint2(0u, 0u);
    }
    *(uint2*)&Wh[(size_t)row * D_SIZE + k]     = h0;
    *(uint2*)&Wh[(size_t)row * D_SIZE + k + 4] = h1;
    *(uint2*)&Wl[(size_t)row * D_SIZE + k]     = l0;
    *(uint2*)&Wl[(size_t)row * D_SIZE + k + 4] = l1;
}

// ---------------- K0: softmax over leaf_params rows -> Q, logQt (transposed) ----------------
__global__ __launch_bounds__(128) void softmax_kernel(
    const float* __restrict__ lp, float* __restrict__ Q, float* __restrict__ logQt)
{
    int row = blockIdx.x;      // leaf
    int t = threadIdx.x;       // class
    __shared__ float red[128];
    float v = lp[row * C_SIZE + t];
    red[t] = v; __syncthreads();
    for (int s = 64; s > 0; s >>= 1) { if (t < s) red[t] = fmaxf(red[t], red[t + s]); __syncthreads(); }
    float mx = red[0]; __syncthreads();
    float e = expf(v - mx);
    red[t] = e; __syncthreads();
    for (int s = 64; s > 0; s >>= 1) { if (t < s) red[t] += red[t + s]; __syncthreads(); }
    float sum = red[0];
    Q[row * C_SIZE + t] = e / sum;
    logQt[(size_t)t * N_LEAF + row] = (v - mx) - logf(sum);   // [class][leaf]
}

// ---------------- K1: z_part[kz] = x @ W^T partials, fp16-split MFMA ----------------
// BM=64, BN=256 (4 waves x 4 n-frags), BK=32, KSPLIT=4.
// A (x) staged via LDS with fp32->f16 split + prefetch; B read directly global->VGPR
// (pre-split W = 2 MB, L2-resident). No B LDS, no async-LDS in the barrier window.
#define GBM 64
#define GBK 32
#define GKSPLIT 4
#define KCHUNK (D_SIZE / GKSPLIT)   // 512
#define KITERS (KCHUNK / GBK)       // 16
#define LDKA 40   // padded A row stride in u16 (80 B)

__global__ __launch_bounds__(256, 2) void gemm_mfma(
    const float* __restrict__ x, const u16* __restrict__ Wh, const u16* __restrict__ Wl,
    float* __restrict__ zp)
{
    __shared__ __align__(16) u16 sAh[GBM * LDKA];
    __shared__ __align__(16) u16 sAl[GBM * LDKA];

    const int t = threadIdx.x;
    const int lane = t & 63, w = t >> 6;
    const int lr = lane & 15, lq = lane >> 4;
    const int m0 = blockIdx.x * GBM;
    const int kz = blockIdx.z;

    f32x4 acc[4][4];
    #pragma unroll
    for (int mt = 0; mt < 4; ++mt)
        #pragma unroll
        for (int nt = 0; nt < 4; ++nt) acc[mt][nt] = (f32x4){0.f, 0.f, 0.f, 0.f};

    const int arow0 = t >> 3, akq = t & 7;    // 32 rows x 8 chunks of 4 floats
    const int kb0 = kz * KCHUNK;

    // prologue: load first A tile
    float4 av0 = *(const float4*)(x + (size_t)(m0 + arow0) * D_SIZE + kb0 + akq * 4);
    float4 av1 = *(const float4*)(x + (size_t)(m0 + 32 + arow0) * D_SIZE + kb0 + akq * 4);

    for (int kt = 0; kt < KITERS; ++kt) {
        const int kb = kb0 + kt * GBK;
        __syncthreads();   // previous iteration's LDS reads done
        {
            uint2 hi, lo;
            split4(av0, hi, lo);
            *(uint2*)&sAh[arow0 * LDKA + akq * 4] = hi;
            *(uint2*)&sAl[arow0 * LDKA + akq * 4] = lo;
            split4(av1, hi, lo);
            *(uint2*)&sAh[(arow0 + 32) * LDKA + akq * 4] = hi;
            *(uint2*)&sAl[(arow0 + 32) * LDKA + akq * 4] = lo;
        }
        __syncthreads();
        // prefetch next A tile (consumed at next iteration's split)
        if (kt + 1 < KITERS) {
            av0 = *(const float4*)(x + (size_t)(m0 + arow0) * D_SIZE + kb + GBK + akq * 4);
            av1 = *(const float4*)(x + (size_t)(m0 + 32 + arow0) * D_SIZE + kb + GBK + akq * 4);
        }
        // B fragments: direct global->VGPR, 16B per lane (L2-resident W)
        half8 bh[4], bl[4];
        #pragma unroll
        for (int nt = 0; nt < 4; ++nt) {
            int row = w * 64 + nt * 16 + lr;
            const u16* src = Wh + (size_t)row * D_SIZE + kb + lq * 8;
            bh[nt] = *(const half8*)src;
            const u16* srcl = Wl + (size_t)row * D_SIZE + kb + lq * 8;
            bl[nt] = *(const half8*)srcl;
        }
        // A fragments from LDS
        half8 ah[4], al[4];
        #pragma unroll
        for (int mt = 0; mt < 4; ++mt) {
            int off = (mt * 16 + lr) * LDKA + lq * 8;
            ah[mt] = *(const half8*)&sAh[off];
            al[mt] = *(const half8*)&sAl[off];
        }
        #pragma unroll
        for (int mt = 0; mt < 4; ++mt)
            #pragma unroll
            for (int nt = 0; nt < 4; ++nt) {
                acc[mt][nt] = __builtin_amdgcn_mfma_f32_16x16x32_f16(ah[mt], bh[nt], acc[mt][nt], 0, 0, 0);
                acc[mt][nt] = __builtin_amdgcn_mfma_f32_16x16x32_f16(ah[mt], bl[nt], acc[mt][nt], 0, 0, 0);
                acc[mt][nt] = __builtin_amdgcn_mfma_f32_16x16x32_f16(al[mt], bh[nt], acc[mt][nt], 0, 0, 0);
            }
    }

    float* zout = zp + (size_t)kz * B_SIZE * NPAD;
    #pragma unroll
    for (int mt = 0; mt < 4; ++mt) {
        #pragma unroll
        for (int nt = 0; nt < 4; ++nt) {
            int gn = w * 64 + nt * 16 + lr;
            #pragma unroll
            for (int r = 0; r < 4; ++r) {
                int gm = m0 + mt * 16 + lq * 4 + r;
                zout[(size_t)gm * NPAD + gn] = acc[mt][nt][r];
            }
        }
    }
}

// ---------------- K2: fused reduce + sigmoid + paths + penalties + loss + argmax gather ----------------
// 512 blocks x 4 waves x 4 rows. NO global atomics: per-block partial record (256 floats):
// [0..126]=pen_num, [127]=loss, [128..254]=pen_den, [255]=0.
__global__ __launch_bounds__(256) void path_kernel(
    const float* __restrict__ z, const int* __restrict__ target,
    const float* __restrict__ bvec, const float* __restrict__ beta,
    const float* __restrict__ Q, const float* __restrict__ logQt,
    float* __restrict__ partial, float* __restrict__ out)
{
    __shared__ float pbuf[4][256];
    __shared__ float s_num[128], s_den[128], s_loss;
    const int t = threadIdx.x, w = t >> 6, lane = t & 63;
    const int c0 = lane * 4;
    float pnum[4] = {0.f, 0.f, 0.f, 0.f};
    float pden[4] = {0.f, 0.f, 0.f, 0.f};
    float loss = 0.f;

    if (t < 128) s_num[t] = 0.f;
    else s_den[t - 128] = 0.f;
    if (t == 0) s_loss = 0.f;

    float bet[4], bia[4];
    #pragma unroll
    for (int j = 0; j < 4; ++j) {
        int c = c0 + j;
        bet[j] = (c < N_INNER) ? beta[c] : 0.f;
        bia[j] = (c < N_INNER) ? bvec[c] : 0.f;
    }

    for (int i = 0; i < 4; ++i) {
        int r = blockIdx.x * 16 + w * 4 + i;
        float4 s = make_float4(0.f, 0.f, 0.f, 0.f);
        #pragma unroll
        for (int p = 0; p < GKSPLIT; ++p) {
            float4 v = *(const float4*)(z + ((size_t)p * B_SIZE + r) * NPAD + c0);
            s.x += v.x; s.y += v.y; s.z += v.z; s.w += v.w;
        }
        float zv[4] = {s.x, s.y, s.z, s.w};
        float pv[4];
        #pragma unroll
        for (int j = 0; j < 4; ++j) {
            int c = c0 + j;
            pv[j] = (c < N_INNER) ? 1.f / (1.f + expf(-bet[j] * (zv[j] + bia[j]))) : 0.f;
        }
        *(float4*)&pbuf[w][c0] = make_float4(pv[0], pv[1], pv[2], pv[3]);
        __syncthreads();

        int tg = target[r];
        float4 lq4 = *(const float4*)(logQt + (size_t)tg * N_LEAF + c0);
        float lqa[4] = {lq4.x, lq4.y, lq4.z, lq4.w};
        float lsum = 0.f, bestV = -1.f;
        int bestI = 0;
        #pragma unroll
        for (int j = 0; j < 4; ++j) {
            int leaf = c0 + j;
            float pl = 1.f;
            #pragma unroll
            for (int d = 0; d < 8; ++d) {
                int node = (1 << d) - 1 + (leaf >> (8 - d));
                int bit = (leaf >> (7 - d)) & 1;
                float pvn = pbuf[w][node];
                pl *= bit ? pvn : (1.f - pvn);
            }
            lsum += pl * lqa[j];
            if (pl > bestV) { bestV = pl; bestI = leaf; }  // ascending j keeps lowest tie
        }
        if (lane < 32) {
            #pragma unroll
            for (int j = 0; j < 4; ++j) {
                int c = c0 + j;
                if (c < 127) {
                    int h = c + 1; int d = 31 - __clz(h);
                    float pp = 1.f;
                    for (int e = 0; e < d; ++e) {
                        int ha = h >> (d - e);
                        int bit = (h >> (d - 1 - e)) & 1;
                        float pvn = pbuf[w][ha - 1];
                        pp *= bit ? pvn : (1.f - pvn);
                    }
                    pnum[j] += pbuf[w][c] * pp;
                    pden[j] += pp;
                }
            }
        }
        #pragma unroll
        for (int m = 1; m < 64; m <<= 1) {
            lsum += __shfl_xor(lsum, m, 64);
            float ov = __shfl_xor(bestV, m, 64);
            int   oi = __shfl_xor(bestI, m, 64);
            if (ov > bestV || (ov == bestV && oi < bestI)) { bestV = ov; bestI = oi; }
        }
        loss += lsum;
        out[1 + (size_t)r * C_SIZE + lane]      = Q[bestI * C_SIZE + lane];
        out[1 + (size_t)r * C_SIZE + lane + 64] = Q[bestI * C_SIZE + lane + 64];
        __syncthreads();
    }

    // block-level reduction via LDS atomics (cheap), one global store per thread
    if (lane < 32) {
        #pragma unroll
        for (int j = 0; j < 4; ++j) {
            int c = c0 + j;
            if (c < 127) {
                atomicAdd(&s_num[c], pnum[j]);
                atomicAdd(&s_den[c], pden[j]);
            }
        }
    }
    if (lane == 0) atomicAdd(&s_loss, loss);
    __syncthreads();
    float* rec = partial + (size_t)blockIdx.x * 256;
    if (t < 127)        rec[t] = s_num[t];
    else if (t == 127)  rec[127] = s_loss;
    else if (t < 255)   rec[t] = s_den[t - 128];
    else                rec[255] = 0.f;
}

// ---------------- K3: reduce partials + finalize total ----------------
__global__ __launch_bounds__(256) void reduce_kernel(
    const float* __restrict__ partial, float* __restrict__ out)
{
    __shared__ float s[256];
    __shared__ float red[128];
    int t = threadIdx.x;
    float a0 = 0.f, a1 = 0.f, a2 = 0.f, a3 = 0.f;
    for (int r = 0; r < NBLK_PATH; r += 4) {
        a0 += partial[(size_t)(r + 0) * 256 + t];
        a1 += partial[(size_t)(r + 1) * 256 + t];
        a2 += partial[(size_t)(r + 2) * 256 + t];
        a3 += partial[(size_t)(r + 3) * 256 + t];
    }
    s[t] = (a0 + a1) + (a2 + a3);
    __syncthreads();
    float term = 0.f;
    if (t < 127) {
        int d = 31 - __clz(t + 1);
        float lam = 0.1f * exp2f(-(float)(d + 1));
        float pen = s[t] / s[128 + t];
        term = lam * 0.5f * (logf(pen) + logf(1.f - pen));
    }
    if (t < 128) { red[t] = term; }
    __syncthreads();
    for (int sh = 64; sh > 0; sh >>= 1) { if (t < sh) red[t] += red[t + sh]; __syncthreads(); }
    if (t == 0) out[0] = -(s[127] / (float)B_SIZE) - red[0];
}

extern "C" void kernel_launch(void* const* d_in, const int* in_sizes, int n_in,
                              void* d_out, int out_size, void* d_ws, size_t ws_size,
                              hipStream_t stream)
{
    const float* x    = (const float*)d_in[0];
    const int*   tgt  = (const int*)d_in[1];
    const float* W    = (const float*)d_in[2];
    const float* b    = (const float*)d_in[3];
    const float* beta = (const float*)d_in[4];
    const float* lp   = (const float*)d_in[5];
    float* out = (float*)d_out;

    // ws layout (floats): z partials (4 x 8192 x 256), Q (256x128), logQt (128x256),
    // Wh/Wl (u16 256x2048 each), block partials (512 x 256)
    float* z     = (float*)d_ws;
    float* Q     = z + (size_t)GKSPLIT * B_SIZE * NPAD;
    float* logQt = Q + (size_t)N_LEAF * C_SIZE;
    u16*   Wh    = (u16*)(logQt + (size_t)C_SIZE * N_LEAF);
    u16*   Wl    = Wh + (size_t)N_LEAF * D_SIZE;
    float* partial = (float*)(Wl + (size_t)N_LEAF * D_SIZE);

    split_w_kernel<<<N_LEAF, 256, 0, stream>>>(W, Wh, Wl);
    softmax_kernel<<<N_LEAF, 128, 0, stream>>>(lp, Q, logQt);

    dim3 ggrid(B_SIZE / GBM, 1, GKSPLIT);   // 128 x 1 x 4 = 512 blocks
    gemm_mfma<<<ggrid, 256, 0, stream>>>(x, Wh, Wl, z);

    path_kernel<<<NBLK_PATH, 256, 0, stream>>>(
        z, tgt, b, beta, Q, logQt, partial, out);

    reduce_kernel<<<1, 256, 0, stream>>>(partial, out);
}

// Round 7
// 180.734 us; speedup vs baseline: 2.0071x; 1.0212x over previous
//
#include <hip/hip_runtime.h>
#include <hip/hip_bf16.h>
#include <hip/hip_fp16.h>
#include <stdint.h>

#define B_SIZE 8192
#define D_SIZE 2048
#define C_SIZE 128
#define N_INNER 255
#define N_LEAF 256
#define NPAD 256
#define NBLK_PATH 512

typedef _Float16 half8 __attribute__((ext_vector_type(8)));
typedef __fp16 pk16x2 __attribute__((ext_vector_type(2)));   // return type of cvt_pkrtz
typedef float f32x4 __attribute__((ext_vector_type(4)));
typedef unsigned short u16;

// ---- fp32 -> (hi,lo) fp16 split, packed pairs ----
__device__ inline uint32_t pkh(float a, float b) {
    pk16x2 h = __builtin_amdgcn_cvt_pkrtz(a, b);
    return __builtin_bit_cast(uint32_t, h);
}
__device__ inline void split4(const float4 v, uint2& hi, uint2& lo) {
    pk16x2 a01 = __builtin_amdgcn_cvt_pkrtz(v.x, v.y);
    pk16x2 a23 = __builtin_amdgcn_cvt_pkrtz(v.z, v.w);
    float r0 = v.x - (float)a01[0];
    float r1 = v.y - (float)a01[1];
    float r2 = v.z - (float)a23[0];
    float r3 = v.w - (float)a23[1];
    hi = make_uint2(__builtin_bit_cast(uint32_t, a01), __builtin_bit_cast(uint32_t, a23));
    lo = make_uint2(pkh(r0, r1), pkh(r2, r3));
}

// ---------------- K-pre (merged): split W -> Wh/Wl  AND  softmax -> Q, logQt ----------------
__global__ __launch_bounds__(256) void prep_kernel(
    const float* __restrict__ Wsrc, u16* __restrict__ Wh, u16* __restrict__ Wl,
    const float* __restrict__ lp, float* __restrict__ Q, float* __restrict__ logQt)
{
    int bid = blockIdx.x;
    int t = threadIdx.x;
    if (bid < 256) {
        // W split: row = bid, each thread 8 k
        int row = bid;
        int k = t * 8;
        uint2 h0, l0, h1, l1;
        if (row < N_INNER) {
            float4 v0 = *(const float4*)(Wsrc + (size_t)row * D_SIZE + k);
            float4 v1 = *(const float4*)(Wsrc + (size_t)row * D_SIZE + k + 4);
            split4(v0, h0, l0); split4(v1, h1, l1);
        } else {
            h0 = l0 = h1 = l1 = make_uint2(0u, 0u);
        }
        *(uint2*)&Wh[(size_t)row * D_SIZE + k]     = h0;
        *(uint2*)&Wh[(size_t)row * D_SIZE + k + 4] = h1;
        *(uint2*)&Wl[(size_t)row * D_SIZE + k]     = l0;
        *(uint2*)&Wl[(size_t)row * D_SIZE + k + 4] = l1;
    } else {
        // softmax over leaf row (bid-256); threads 0..127 work, all hit barriers
        int row = bid - 256;
        __shared__ float red[128];
        float v = 0.f;
        if (t < 128) { v = lp[row * C_SIZE + t]; red[t] = v; }
        __syncthreads();
        for (int s = 64; s > 0; s >>= 1) { if (t < s) red[t] = fmaxf(red[t], red[t + s]); __syncthreads(); }
        float mx = red[0]; __syncthreads();
        float e = 0.f;
        if (t < 128) { e = expf(v - mx); red[t] = e; }
        __syncthreads();
        for (int s = 64; s > 0; s >>= 1) { if (t < s) red[t] += red[t + s]; __syncthreads(); }
        float sum = red[0];
        if (t < 128) {
            Q[row * C_SIZE + t] = e / sum;
            logQt[(size_t)t * N_LEAF + row] = (v - mx) - logf(sum);   // [class][leaf]
        }
    }
}

// ---------------- K1: z_part[kz] = x @ W^T partials, fp16-split MFMA, BARRIER-FREE ----------------
// BM=64, N=256 (4 waves x 64 cols), BK=32, KSPLIT=4. A staged into WAVE-PRIVATE LDS
// (4x dup, zero cross-wave coupling); B direct global->VGPR from L2-resident pre-split W.
// No __syncthreads in the K-loop: DS is in-order per wave; lgkmcnt(0) fence only.
#define GBM 64
#define GBK 32
#define GKSPLIT 4
#define KCHUNK (D_SIZE / GKSPLIT)   // 512
#define KITERS (KCHUNK / GBK)       // 16
#define LDKA 40                     // padded A row stride in u16 (80 B -> 2-way bank alias = free)

__global__ __launch_bounds__(256, 2) void gemm_mfma(
    const float* __restrict__ x, const u16* __restrict__ Wh, const u16* __restrict__ Wl,
    float* __restrict__ zp)
{
    __shared__ __align__(16) u16 sAh[4][GBM * LDKA];
    __shared__ __align__(16) u16 sAl[4][GBM * LDKA];

    const int t = threadIdx.x;
    const int lane = t & 63, w = t >> 6;
    const int lr = lane & 15, lq = lane >> 4;
    const int m0 = blockIdx.x * GBM;
    const int kz = blockIdx.z;
    const int kb0 = kz * KCHUNK;

    f32x4 acc[4][4];
    #pragma unroll
    for (int mt = 0; mt < 4; ++mt)
        #pragma unroll
        for (int nt = 0; nt < 4; ++nt) acc[mt][nt] = (f32x4){0.f, 0.f, 0.f, 0.f};

    // prologue: load first A tile (64 rows x 32 k fp32, 8 float4/lane, coalesced 8 lanes/row)
    float4 av_c[8];
    #pragma unroll
    for (int i = 0; i < 8; ++i) {
        int idx = i * 64 + lane;
        int row = idx >> 3, ch = idx & 7;
        av_c[i] = *(const float4*)(x + (size_t)(m0 + row) * D_SIZE + kb0 + ch * 4);
    }

    #pragma unroll
    for (int kt = 0; kt < KITERS; ++kt) {
        const int kb = kb0 + kt * GBK;
        // B fragments for this kt: direct global->VGPR (16 rows x 64B full segments)
        half8 bh[4], bl[4];
        #pragma unroll
        for (int nt = 0; nt < 4; ++nt) {
            int row = w * 64 + nt * 16 + lr;
            bh[nt] = *(const half8*)(Wh + (size_t)row * D_SIZE + kb + lq * 8);
            bl[nt] = *(const half8*)(Wl + (size_t)row * D_SIZE + kb + lq * 8);
        }
        // prefetch next A tile into regs (consumed next iteration)
        float4 av_n[8];
        if (kt + 1 < KITERS) {
            #pragma unroll
            for (int i = 0; i < 8; ++i) {
                int idx = i * 64 + lane;
                int row = idx >> 3, ch = idx & 7;
                av_n[i] = *(const float4*)(x + (size_t)(m0 + row) * D_SIZE + kb + GBK + ch * 4);
            }
        }
        // split current A into this wave's private LDS region
        #pragma unroll
        for (int i = 0; i < 8; ++i) {
            int idx = i * 64 + lane;
            int row = idx >> 3, ch = idx & 7;
            uint2 hi, lo; split4(av_c[i], hi, lo);
            *(uint2*)&sAh[w][row * LDKA + ch * 4] = hi;
            *(uint2*)&sAl[w][row * LDKA + ch * 4] = lo;
        }
        asm volatile("s_waitcnt lgkmcnt(0)" ::: "memory");  // wave-sync LDS: writes visible to own wave
        // A fragments
        half8 ah[4], al[4];
        #pragma unroll
        for (int mt = 0; mt < 4; ++mt) {
            int off = (mt * 16 + lr) * LDKA + lq * 8;
            ah[mt] = *(const half8*)&sAh[w][off];
            al[mt] = *(const half8*)&sAl[w][off];
        }
        #pragma unroll
        for (int mt = 0; mt < 4; ++mt)
            #pragma unroll
            for (int nt = 0; nt < 4; ++nt) {
                acc[mt][nt] = __builtin_amdgcn_mfma_f32_16x16x32_f16(ah[mt], bh[nt], acc[mt][nt], 0, 0, 0);
                acc[mt][nt] = __builtin_amdgcn_mfma_f32_16x16x32_f16(ah[mt], bl[nt], acc[mt][nt], 0, 0, 0);
                acc[mt][nt] = __builtin_amdgcn_mfma_f32_16x16x32_f16(al[mt], bh[nt], acc[mt][nt], 0, 0, 0);
            }
        if (kt + 1 < KITERS) {
            #pragma unroll
            for (int i = 0; i < 8; ++i) av_c[i] = av_n[i];
        }
    }

    float* zout = zp + (size_t)kz * B_SIZE * NPAD;
    #pragma unroll
    for (int mt = 0; mt < 4; ++mt) {
        #pragma unroll
        for (int nt = 0; nt < 4; ++nt) {
            int gn = w * 64 + nt * 16 + lr;
            #pragma unroll
            for (int r = 0; r < 4; ++r) {
                int gm = m0 + mt * 16 + lq * 4 + r;
                zout[(size_t)gm * NPAD + gn] = acc[mt][nt][r];
            }
        }
    }
}

// ---------------- K2: fused reduce + sigmoid + paths + penalties + loss + argmax gather ----------------
// 512 blocks x 4 waves x 4 rows. pbuf wave-private -> no per-iter barriers (lgkm fence only).
// One real __syncthreads after LDS-accumulator init, one before the partial write-out.
__global__ __launch_bounds__(256) void path_kernel(
    const float* __restrict__ z, const int* __restrict__ target,
    const float* __restrict__ bvec, const float* __restrict__ beta,
    const float* __restrict__ Q, const float* __restrict__ logQt,
    float* __restrict__ partial, float* __restrict__ out)
{
    __shared__ float pbuf[4][256];
    __shared__ float s_num[128], s_den[128], s_loss;
    const int t = threadIdx.x, w = t >> 6, lane = t & 63;
    const int c0 = lane * 4;
    float pnum[4] = {0.f, 0.f, 0.f, 0.f};
    float pden[4] = {0.f, 0.f, 0.f, 0.f};
    float loss = 0.f;

    if (t < 128) s_num[t] = 0.f;
    else s_den[t - 128] = 0.f;
    if (t == 0) s_loss = 0.f;
    __syncthreads();   // init visible to all waves before end-of-kernel atomics

    float bet[4], bia[4];
    #pragma unroll
    for (int j = 0; j < 4; ++j) {
        int c = c0 + j;
        bet[j] = (c < N_INNER) ? beta[c] : 0.f;
        bia[j] = (c < N_INNER) ? bvec[c] : 0.f;
    }

    for (int i = 0; i < 4; ++i) {
        int r = blockIdx.x * 16 + w * 4 + i;
        float4 s = make_float4(0.f, 0.f, 0.f, 0.f);
        #pragma unroll
        for (int p = 0; p < GKSPLIT; ++p) {
            float4 v = *(const float4*)(z + ((size_t)p * B_SIZE + r) * NPAD + c0);
            s.x += v.x; s.y += v.y; s.z += v.z; s.w += v.w;
        }
        float zv[4] = {s.x, s.y, s.z, s.w};
        float pv[4];
        #pragma unroll
        for (int j = 0; j < 4; ++j) {
            int c = c0 + j;
            pv[j] = (c < N_INNER) ? 1.f / (1.f + expf(-bet[j] * (zv[j] + bia[j]))) : 0.f;
        }
        *(float4*)&pbuf[w][c0] = make_float4(pv[0], pv[1], pv[2], pv[3]);
        asm volatile("s_waitcnt lgkmcnt(0)" ::: "memory");  // wave-private LDS visibility

        int tg = target[r];
        float4 lq4 = *(const float4*)(logQt + (size_t)tg * N_LEAF + c0);
        float lqa[4] = {lq4.x, lq4.y, lq4.z, lq4.w};
        float lsum = 0.f, bestV = -1.f;
        int bestI = 0;
        #pragma unroll
        for (int j = 0; j < 4; ++j) {
            int leaf = c0 + j;
            float pl = 1.f;
            #pragma unroll
            for (int d = 0; d < 8; ++d) {
                int node = (1 << d) - 1 + (leaf >> (8 - d));
                int bit = (leaf >> (7 - d)) & 1;
                float pvn = pbuf[w][node];
                pl *= bit ? pvn : (1.f - pvn);
            }
            lsum += pl * lqa[j];
            if (pl > bestV) { bestV = pl; bestI = leaf; }  // ascending j keeps lowest tie
        }
        if (lane < 32) {
            #pragma unroll
            for (int j = 0; j < 4; ++j) {
                int c = c0 + j;
                if (c < 127) {
                    int h = c + 1; int d = 31 - __clz(h);
                    float pp = 1.f;
                    for (int e = 0; e < d; ++e) {
                        int ha = h >> (d - e);
                        int bit = (h >> (d - 1 - e)) & 1;
                        float pvn = pbuf[w][ha - 1];
                        pp *= bit ? pvn : (1.f - pvn);
                    }
                    pnum[j] += pbuf[w][c] * pp;
                    pden[j] += pp;
                }
            }
        }
        #pragma unroll
        for (int m = 1; m < 64; m <<= 1) {
            lsum += __shfl_xor(lsum, m, 64);
            float ov = __shfl_xor(bestV, m, 64);
            int   oi = __shfl_xor(bestI, m, 64);
            if (ov > bestV || (ov == bestV && oi < bestI)) { bestV = ov; bestI = oi; }
        }
        loss += lsum;
        out[1 + (size_t)r * C_SIZE + lane]      = Q[bestI * C_SIZE + lane];
        out[1 + (size_t)r * C_SIZE + lane + 64] = Q[bestI * C_SIZE + lane + 64];
        asm volatile("" ::: "memory");  // keep next iter's pbuf write after this iter's reads
    }

    // block-level reduction via LDS atomics, then one global store per thread
    if (lane < 32) {
        #pragma unroll
        for (int j = 0; j < 4; ++j) {
            int c = c0 + j;
            if (c < 127) {
                atomicAdd(&s_num[c], pnum[j]);
                atomicAdd(&s_den[c], pden[j]);
            }
        }
    }
    if (lane == 0) atomicAdd(&s_loss, loss);
    __syncthreads();
    float* rec = partial + (size_t)blockIdx.x * 256;
    if (t < 127)        rec[t] = s_num[t];
    else if (t == 127)  rec[127] = s_loss;
    else if (t < 255)   rec[t] = s_den[t - 128];
    else                rec[255] = 0.f;
}

// ---------------- K3: reduce partials + finalize total ----------------
__global__ __launch_bounds__(256) void reduce_kernel(
    const float* __restrict__ partial, float* __restrict__ out)
{
    __shared__ float s[256];
    __shared__ float red[128];
    int t = threadIdx.x;
    float a0 = 0.f, a1 = 0.f, a2 = 0.f, a3 = 0.f;
    for (int r = 0; r < NBLK_PATH; r += 4) {
        a0 += partial[(size_t)(r + 0) * 256 + t];
        a1 += partial[(size_t)(r + 1) * 256 + t];
        a2 += partial[(size_t)(r + 2) * 256 + t];
        a3 += partial[(size_t)(r + 3) * 256 + t];
    }
    s[t] = (a0 + a1) + (a2 + a3);
    __syncthreads();
    float term = 0.f;
    if (t < 127) {
        int d = 31 - __clz(t + 1);
        float lam = 0.1f * exp2f(-(float)(d + 1));
        float pen = s[t] / s[128 + t];
        term = lam * 0.5f * (logf(pen) + logf(1.f - pen));
    }
    if (t < 128) { red[t] = term; }
    __syncthreads();
    for (int sh = 64; sh > 0; sh >>= 1) { if (t < sh) red[t] += red[t + sh]; __syncthreads(); }
    if (t == 0) out[0] = -(s[127] / (float)B_SIZE) - red[0];
}

extern "C" void kernel_launch(void* const* d_in, const int* in_sizes, int n_in,
                              void* d_out, int out_size, void* d_ws, size_t ws_size,
                              hipStream_t stream)
{
    const float* x    = (const float*)d_in[0];
    const int*   tgt  = (const int*)d_in[1];
    const float* W    = (const float*)d_in[2];
    const float* b    = (const float*)d_in[3];
    const float* beta = (const float*)d_in[4];
    const float* lp   = (const float*)d_in[5];
    float* out = (float*)d_out;

    // ws layout (floats): z partials (4 x 8192 x 256), Q (256x128), logQt (128x256),
    // Wh/Wl (u16 256x2048 each), block partials (512 x 256)
    float* z     = (float*)d_ws;
    float* Q     = z + (size_t)GKSPLIT * B_SIZE * NPAD;
    float* logQt = Q + (size_t)N_LEAF * C_SIZE;
    u16*   Wh    = (u16*)(logQt + (size_t)C_SIZE * N_LEAF);
    u16*   Wl    = Wh + (size_t)N_LEAF * D_SIZE;
    float* partial = (float*)(Wl + (size_t)N_LEAF * D_SIZE);

    prep_kernel<<<512, 256, 0, stream>>>(W, Wh, Wl, lp, Q, logQt);

    dim3 ggrid(B_SIZE / GBM, 1, GKSPLIT);   // 128 x 1 x 4 = 512 blocks
    gemm_mfma<<<ggrid, 256, 0, stream>>>(x, Wh, Wl, z);

    path_kernel<<<NBLK_PATH, 256, 0, stream>>>(
        z, tgt, b, beta, Q, logQt, partial, out);

    reduce_kernel<<<1, 256, 0, stream>>>(partial, out);
}